// Round 20
// baseline (47.251 us; speedup 1.0000x reference)
//
#include <hip/hip_runtime.h>

#define MDIM 4096
#define NDIM 4096
#define NCOEF 768
#define ALPHA 16.0f
#define PANEL_I8 (12 * 16384)      // bytes per 256-row/col panel (12 K-slabs x 16 KB)

typedef __attribute__((ext_vector_type(4))) int   i32x4;
typedef __attribute__((ext_vector_type(4))) float f32x4;

__device__ __forceinline__ void glds16c(const char* src, char* dst) {
    __builtin_amdgcn_global_load_lds(
        (const __attribute__((address_space(1))) void*)src,
        (__attribute__((address_space(3))) void*)dst, 16, 0, 0);
}

// ---- kernel 1: materialize U,V as INT8 (meta fused; unchanged from R17) ----
__global__ __launch_bounds__(256) void fill_uv(
    const int* __restrict__ fidx, const float* __restrict__ dw,
    char* __restrict__ U8, char* __restrict__ V8, float* __restrict__ csp)
{
    __shared__ int idx_s[NCOEF];
    __shared__ float red[4];
    __shared__ int dup[16];
    __shared__ float su_l[16], sv_l[16];
    const int b = blockIdx.x;
    const int panel = b / 48;
    const int rem = b - panel * 48;
    const int kt = rem >> 2;
    const int k16 = rem & 3;
    const int p0 = kt * 64 + (k16 << 4);
    const int t = threadIdx.x;
    float m = 0.0f;
    #pragma unroll
    for (int j = 0; j < 3; ++j) {
        idx_s[t + (j << 8)] = fidx[t + (j << 8)];
        m = fmaxf(m, fabsf(dw[t + (j << 8)]));
    }
    if (t < 16) dup[t] = 0;
    #pragma unroll
    for (int off = 32; off > 0; off >>= 1) m = fmaxf(m, __shfl_xor(m, off));
    if ((t & 63) == 0) red[t >> 6] = m;
    __syncthreads();
    const float maxdw = fmaxf(fmaxf(red[0], red[1]), fmaxf(red[2], red[3]));
    {
        const int ci = t >> 4;
        const int pci = p0 + ci;
        const int myidx = idx_s[pci];
        const int q0 = (t & 15) * 48;
        int found = 0;
        #pragma unroll
        for (int s = 0; s < 48; ++s) {
            const int q = q0 + s;
            found |= (q > pci) & (idx_s[q] == myidx);
        }
        if (found) dup[ci] = 1;
    }
    __syncthreads();
    const float s0 = 0.015625f;
    const float s1 = 0.022097086912079612f;
    const float Vmax = ALPHA * maxdw * s1;
    const float isV = (Vmax > 0.0f) ? (127.0f / Vmax) : 0.0f;
    if (t < 16) {
        const int p = p0 + t;
        const int idx = idx_s[p];
        const int r = idx >> 12;
        const int c = idx & (NDIM - 1);
        su_l[t] = ((r == 0) ? s0 : s1) * (127.0f / s1);
        sv_l[t] = (dup[t] ? 0.0f : 1.0f) * ALPHA * dw[p] * ((c == 0) ? s0 : s1) * isV;
    }
    if (b == 0 && t == 0) csp[0] = (s1 / 127.0f) * (Vmax / 127.0f);
    __syncthreads();
    const unsigned tt = 2u * (unsigned)((panel << 8) + t) + 1u;
    const float wrev = 1.0f / 16384.0f;
    unsigned wu[4] = {0, 0, 0, 0}, wv[4] = {0, 0, 0, 0};
    #pragma unroll
    for (int j = 0; j < 16; ++j) {
        const int idx = idx_s[p0 + j];
        const unsigned nu = (tt * (unsigned)(idx >> 12)) & 16383u;
        const unsigned nv = (tt * (unsigned)(idx & (NDIM - 1))) & 16383u;
        const int qu = (int)rintf(su_l[j] * __builtin_amdgcn_cosf((float)nu * wrev));
        const int qv = (int)rintf(sv_l[j] * __builtin_amdgcn_cosf((float)nv * wrev));
        wu[j >> 2] |= (unsigned)(qu & 255) << ((j & 3) * 8);
        wv[j >> 2] |= (unsigned)(qv & 255) << ((j & 3) * 8);
    }
    const size_t off = ((size_t)(panel * 12 + kt) * 1024 + (size_t)(k16 << 8) + t) << 4;
    *(uint4*)(U8 + off) = make_uint4(wu[0], wu[1], wu[2], wu[3]);
    *(uint4*)(V8 + off) = make_uint4(wv[0], wv[1], wv[2], wv[3]);
}

// ---- kernel 2: out = W + CS*(U8 @ V8^T), wave-specialized two-tile ----
// Waves 0-3 own tile A (cols +0..128), waves 4-7 tile B (cols +128..256);
// each wave holds ONE acc[8][4] (128 regs) -> no spill. Phase 1 (iters
// 0-11): A computes, B stages. Phase 2 (12-23): A stages + runs tile-A's
// epilogue inline (3-region L rotation, NT W-loads/out-stores; wave-local
// counted vmcnt); B computes. Tail: tile-B epilogue, raw-barrier pipelined.
__global__ __launch_bounds__(512, 1) void gemm_kernel(
    const float* __restrict__ W,
    const char* __restrict__ U8,
    const char* __restrict__ V8,
    const float* __restrict__ csp,
    float* __restrict__ out)
{
    __shared__ char SM[148992];          // As 64K | Bs 32K | L 3x16896
    char* const As = SM;                 // 4 bufs x 16384 B (256 rows x 64 k)
    char* const Bs = SM + 65536;         // 4 bufs x 8192 B (128 cols x 64 k)
    float* const L = (float*)(SM + 98304);   // 3 regions x 32 x 132 f32

    const int tid = threadIdx.x;         // 0..511
    const int lane = tid & 63;
    const int wave = tid >> 6;           // 0..7
    const bool isA = wave < 4;
    const int wl = wave & 3;
    const int wr = (wave >> 1) & 1;
    const int wc = wave & 1;
    const int fr = lane & 15;
    const int fks = lane >> 4;

    // XCD rect swizzle: 256 blocks, 8 XCDs, 4(by) x 8(bxp) rect per XCD.
    const int bid = blockIdx.x;
    const int xcd = bid & 7;
    const int local = bid >> 3;
    const int by = ((xcd >> 1) << 2) + (local >> 3);
    const int bxp = ((xcd & 1) << 3) + (local & 7);

    const char* uPan = U8 + (size_t)by * PANEL_I8;
    const char* vPan = V8 + (size_t)bxp * PANEL_I8;
    const float CS = *csp;

    i32x4 acc[8][4] = {};                // tile A for waves 0-3, B for 4-7
    f32x4 wregA[2][4];
    f32x4 wregB[2][2];

    const int aO = (fks << 12) + ((wr * 128 + fr) << 4);
    const int bO = (fks << 11) + ((wc * 64 + fr) << 4);

    const int erow = by << 8;
    const int bcolA = bxp << 8;
    const int bcolB = bcolA + 128;

#define VWAIT(n) asm volatile("s_waitcnt vmcnt(" #n ")" ::: "memory")
#define LGKM()   asm volatile("s_waitcnt lgkmcnt(0)" ::: "memory")
#define BARR()   do { __builtin_amdgcn_s_barrier(); asm volatile("" ::: "memory"); } while (0)

    // stage slab s: A-content (s%12) -> As buf s&3; V half (s/12) -> Bs buf s&3
#define STAGE_AB(s) do {                                                     \
        const char* uS = uPan + (size_t)((s) % 12) * 16384;                  \
        char* aD = As + ((s) & 3) * 16384 + (wl << 10);                      \
        glds16c(uS + (wl << 10) + (lane << 4),               aD);            \
        glds16c(uS + 4096 + (wl << 10) + (lane << 4),        aD + 4096);     \
        glds16c(uS + 8192 + (wl << 10) + (lane << 4),        aD + 8192);     \
        glds16c(uS + 12288 + (wl << 10) + (lane << 4),       aD + 12288);    \
        const char* vS = vPan + (size_t)((s) % 12) * 16384 + ((s) / 12) * 2048; \
        char* bD = Bs + ((s) & 3) * 8192 + (wl << 10);                       \
        glds16c(vS + (((wl >> 1) + 0) << 12) + ((wl & 1) << 10) + (lane << 4), bD); \
        glds16c(vS + (((wl >> 1) + 2) << 12) + ((wl & 1) << 10) + (lane << 4), bD + 4096); \
    } while (0)

#define COMPUTE(buf) do {                                                    \
        i32x4 a[8], b[4];                                                    \
        _Pragma("unroll")                                                    \
        for (int fm = 0; fm < 8; ++fm)                                       \
            a[fm] = *(const i32x4*)(As + (buf) * 16384 + aO + fm * 256);     \
        _Pragma("unroll")                                                    \
        for (int fn = 0; fn < 4; ++fn)                                       \
            b[fn] = *(const i32x4*)(Bs + (buf) * 8192 + bO + fn * 256);      \
        _Pragma("unroll")                                                    \
        for (int fm = 0; fm < 8; ++fm)                                       \
            _Pragma("unroll")                                                \
            for (int fn = 0; fn < 4; ++fn)                                   \
                acc[fm][fn] = __builtin_amdgcn_mfma_i32_16x16x64_i8(         \
                    b[fn], a[fm], acc[fm][fn], 0, 0, 0);                     \
    } while (0)

    // epilogue-A helpers (256 A-threads; tid < 256)
#define WLA(c) do {                                                          \
        _Pragma("unroll")                                                    \
        for (int i = 0; i < 4; ++i) {                                        \
            const int e = i * 256 + tid;                                     \
            wregA[(c) & 1][i] = __builtin_nontemporal_load((const f32x4*)(   \
                W + (size_t)(erow + (c) * 32 + (e >> 5)) * NDIM              \
                  + bcolA + ((e & 31) << 2)));                               \
        }                                                                    \
    } while (0)
#define LWRA(c) do {                                                         \
        if (wr == ((c) >> 2)) {                                              \
            _Pragma("unroll")                                                \
            for (int f2 = 0; f2 < 2; ++f2)                                   \
                _Pragma("unroll")                                            \
                for (int fn = 0; fn < 4; ++fn) {                             \
                    f32x4 v;                                                 \
                    _Pragma("unroll")                                        \
                    for (int jj = 0; jj < 4; ++jj)                           \
                        v[jj] = CS * (float)acc[((c) & 3) * 2 + f2][fn][jj]; \
                    *(f32x4*)(L + ((c) % 3) * 4224 + (f2 * 16 + fr) * 132    \
                              + (wc << 6) + fn * 16 + (fks << 2)) = v;       \
                }                                                            \
        }                                                                    \
    } while (0)
#define STA(c) do {                                                          \
        _Pragma("unroll")                                                    \
        for (int i = 0; i < 4; ++i) {                                        \
            const int e = i * 256 + tid;                                     \
            const int rl = e >> 5;                                           \
            const int cg = e & 31;                                           \
            const f32x4 l4 = *(const f32x4*)(L + ((c) % 3) * 4224            \
                                             + rl * 132 + (cg << 2));        \
            f32x4 r4 = wregA[(c) & 1][i] + l4;                               \
            __builtin_nontemporal_store(r4, (f32x4*)(                        \
                out + (size_t)(erow + (c) * 32 + rl) * NDIM                  \
                    + bcolA + (cg << 2)));                                   \
        }                                                                    \
    } while (0)

    // epilogue-B helpers (all 512 threads; LWRB only B-waves)
#define WLB(c) do {                                                          \
        _Pragma("unroll")                                                    \
        for (int i = 0; i < 2; ++i) {                                        \
            const int e = i * 512 + tid;                                     \
            wregB[(c) & 1][i] = __builtin_nontemporal_load((const f32x4*)(   \
                W + (size_t)(erow + (c) * 32 + (e >> 5)) * NDIM              \
                  + bcolB + ((e & 31) << 2)));                               \
        }                                                                    \
    } while (0)
#define LWRB(c) do {                                                         \
        if (!isA && wr == ((c) >> 2)) {                                      \
            _Pragma("unroll")                                                \
            for (int f2 = 0; f2 < 2; ++f2)                                   \
                _Pragma("unroll")                                            \
                for (int fn = 0; fn < 4; ++fn) {                             \
                    f32x4 v;                                                 \
                    _Pragma("unroll")                                        \
                    for (int jj = 0; jj < 4; ++jj)                           \
                        v[jj] = CS * (float)acc[((c) & 3) * 2 + f2][fn][jj]; \
                    *(f32x4*)(L + ((c) & 1) * 4224 + (f2 * 16 + fr) * 132    \
                              + (wc << 6) + fn * 16 + (fks << 2)) = v;       \
                }                                                            \
        }                                                                    \
    } while (0)
#define STB(c) do {                                                          \
        _Pragma("unroll")                                                    \
        for (int i = 0; i < 2; ++i) {                                        \
            const int e = i * 512 + tid;                                     \
            const int rl = e >> 5;                                           \
            const int cg = e & 31;                                           \
            const f32x4 l4 = *(const f32x4*)(L + ((c) & 1) * 4224            \
                                             + rl * 132 + (cg << 2));        \
            f32x4 r4 = wregB[(c) & 1][i] + l4;                               \
            __builtin_nontemporal_store(r4, (f32x4*)(                        \
                out + (size_t)(erow + (c) * 32 + rl) * NDIM                  \
                    + bcolB + ((cg) << 2)));                                 \
        }                                                                    \
    } while (0)

    // ---- prologue: B-waves stage slabs 0,1 ----
    if (!isA) { STAGE_AB(0); STAGE_AB(1); VWAIT(6); }
    LGKM(); BARR();

    // ---- phase 1: iters 0..11 — A computes, B stages ----
#define P1(j) do {                                                           \
        if (!isA) { STAGE_AB((j) + 2); VWAIT(12); }                          \
        LGKM(); BARR();                                                      \
        if (isA) COMPUTE((j) & 3);                                           \
    } while (0)
    P1(0); P1(1); P1(2); P1(3); P1(4); P1(5);
    P1(6); P1(7); P1(8); P1(9); P1(10); P1(11);

    // ---- phase 2: iters 12..23 — B computes, A stages + epilogue-A ----
    // A-wave vmcnt audit (WLA=4, STAGE=6, STA=4 ops):
    // i=12 none; i=13 VW(16); i=14..19 VW(20); i=20 VW(16); i=21 VW(20);
    // i=22 VW(10); i=23 VW(0). B-wave: i=12 VW(6); i=13 VW(0); else none.
    if (isA) { WLA(0); STAGE_AB(14); LWRA(0); } else { VWAIT(6); }
    LGKM(); BARR();
    if (!isA) COMPUTE(0);

    if (isA) { WLA(1); STAGE_AB(15); LWRA(1); VWAIT(16); } else { VWAIT(0); }
    LGKM(); BARR();
    if (!isA) COMPUTE(1);
    if (isA) STA(0);

#define P2(i, c) do {                                                        \
        if (isA) { WLA(c); STAGE_AB((i) + 2); LWRA(c); VWAIT(20); }          \
        LGKM(); BARR();                                                      \
        if (!isA) COMPUTE((i) & 3);                                          \
        if (isA) STA((c) - 1);                                               \
    } while (0)
    P2(14, 2); P2(15, 3); P2(16, 4); P2(17, 5); P2(18, 6); P2(19, 7);

    if (isA) { STAGE_AB(22); VWAIT(16); }
    LGKM(); BARR();
    if (!isA) COMPUTE(0);            // 20&3
    if (isA) STA(7);

    if (isA) { STAGE_AB(23); VWAIT(20); }
    LGKM(); BARR();
    if (!isA) COMPUTE(1);            // 21&3

    if (isA) { VWAIT(10); }
    LGKM(); BARR();
    if (!isA) COMPUTE(2);            // 22&3

    if (isA) { VWAIT(0); }
    LGKM(); BARR();
    if (!isA) COMPUTE(3);            // 23&3

    // ---- tail: epilogue-B (all waves stream; B-waves own LWRB) ----
    WLB(0);
    LWRB(0);
    LGKM(); BARR();
    WLB(1); LWRB(1); VWAIT(2); STB(0);
    LGKM(); BARR();
    WLB(2); LWRB(2); VWAIT(4); STB(1);
    LGKM(); BARR();
    WLB(3); LWRB(3); VWAIT(4); STB(2);
    LGKM(); BARR();
    WLB(4); LWRB(4); VWAIT(4); STB(3);
    LGKM(); BARR();
    WLB(5); LWRB(5); VWAIT(4); STB(4);
    LGKM(); BARR();
    WLB(6); LWRB(6); VWAIT(4); STB(5);
    LGKM(); BARR();
    WLB(7); LWRB(7); VWAIT(4); STB(6);
    LGKM(); BARR();
    VWAIT(2); STB(7);

#undef VWAIT
#undef LGKM
#undef BARR
#undef STAGE_AB
#undef COMPUTE
#undef WLA
#undef LWRA
#undef STA
#undef WLB
#undef LWRB
#undef STB
#undef P1
#undef P2
}

extern "C" void kernel_launch(void* const* d_in, const int* in_sizes, int n_in,
                              void* d_out, int out_size, void* d_ws, size_t ws_size,
                              hipStream_t stream) {
    const float* weight = (const float*)d_in[0];
    const float* dw     = (const float*)d_in[1];
    const int*   fidx   = (const int*)d_in[2];
    float* out = (float*)d_out;

    char* ws = (char*)d_ws;
    char* U8 = ws;                               // 3,145,728 B
    char* V8 = ws + 3145728;                     // 3,145,728 B
    float* csp = (float*)(ws + 2 * 3145728);

    fill_uv<<<16 * 48, 256, 0, stream>>>(fidx, dw, U8, V8, csp);
    gemm_kernel<<<256, 512, 0, stream>>>(weight, U8, V8, csp, out);
}

// Round 21
// 47.177 us; speedup vs baseline: 1.0016x; 1.0016x over previous
//
#include <hip/hip_runtime.h>

#define MDIM 4096
#define NDIM 4096
#define NCOEF 768
#define ALPHA 16.0f
#define PANEL_I8 (12 * 16384)      // bytes per 256-row/col panel (12 K-slabs x 16 KB)

typedef __attribute__((ext_vector_type(4))) int   i32x4;
typedef __attribute__((ext_vector_type(4))) float f32x4;

__device__ __forceinline__ void glds16c(const char* src, char* dst) {
    __builtin_amdgcn_global_load_lds(
        (const __attribute__((address_space(1))) void*)src,
        (__attribute__((address_space(3))) void*)dst, 16, 0, 0);
}

// ---- kernel 1: materialize U,V as INT8 (meta fused; unchanged from R17) ----
__global__ __launch_bounds__(256) void fill_uv(
    const int* __restrict__ fidx, const float* __restrict__ dw,
    char* __restrict__ U8, char* __restrict__ V8, float* __restrict__ csp)
{
    __shared__ int idx_s[NCOEF];
    __shared__ float red[4];
    __shared__ int dup[16];
    __shared__ float su_l[16], sv_l[16];
    const int b = blockIdx.x;
    const int panel = b / 48;
    const int rem = b - panel * 48;
    const int kt = rem >> 2;
    const int k16 = rem & 3;
    const int p0 = kt * 64 + (k16 << 4);
    const int t = threadIdx.x;
    float m = 0.0f;
    #pragma unroll
    for (int j = 0; j < 3; ++j) {
        idx_s[t + (j << 8)] = fidx[t + (j << 8)];
        m = fmaxf(m, fabsf(dw[t + (j << 8)]));
    }
    if (t < 16) dup[t] = 0;
    #pragma unroll
    for (int off = 32; off > 0; off >>= 1) m = fmaxf(m, __shfl_xor(m, off));
    if ((t & 63) == 0) red[t >> 6] = m;
    __syncthreads();
    const float maxdw = fmaxf(fmaxf(red[0], red[1]), fmaxf(red[2], red[3]));
    {
        const int ci = t >> 4;
        const int pci = p0 + ci;
        const int myidx = idx_s[pci];
        const int q0 = (t & 15) * 48;
        int found = 0;
        #pragma unroll
        for (int s = 0; s < 48; ++s) {
            const int q = q0 + s;
            found |= (q > pci) & (idx_s[q] == myidx);
        }
        if (found) dup[ci] = 1;
    }
    __syncthreads();
    const float s0 = 0.015625f;
    const float s1 = 0.022097086912079612f;
    const float Vmax = ALPHA * maxdw * s1;
    const float isV = (Vmax > 0.0f) ? (127.0f / Vmax) : 0.0f;
    if (t < 16) {
        const int p = p0 + t;
        const int idx = idx_s[p];
        const int r = idx >> 12;
        const int c = idx & (NDIM - 1);
        su_l[t] = ((r == 0) ? s0 : s1) * (127.0f / s1);
        sv_l[t] = (dup[t] ? 0.0f : 1.0f) * ALPHA * dw[p] * ((c == 0) ? s0 : s1) * isV;
    }
    if (b == 0 && t == 0) csp[0] = (s1 / 127.0f) * (Vmax / 127.0f);
    __syncthreads();
    const unsigned tt = 2u * (unsigned)((panel << 8) + t) + 1u;
    const float wrev = 1.0f / 16384.0f;
    unsigned wu[4] = {0, 0, 0, 0}, wv[4] = {0, 0, 0, 0};
    #pragma unroll
    for (int j = 0; j < 16; ++j) {
        const int idx = idx_s[p0 + j];
        const unsigned nu = (tt * (unsigned)(idx >> 12)) & 16383u;
        const unsigned nv = (tt * (unsigned)(idx & (NDIM - 1))) & 16383u;
        const int qu = (int)rintf(su_l[j] * __builtin_amdgcn_cosf((float)nu * wrev));
        const int qv = (int)rintf(sv_l[j] * __builtin_amdgcn_cosf((float)nv * wrev));
        wu[j >> 2] |= (unsigned)(qu & 255) << ((j & 3) * 8);
        wv[j >> 2] |= (unsigned)(qv & 255) << ((j & 3) * 8);
    }
    const size_t off = ((size_t)(panel * 12 + kt) * 1024 + (size_t)(k16 << 8) + t) << 4;
    *(uint4*)(U8 + off) = make_uint4(wu[0], wu[1], wu[2], wu[3]);
    *(uint4*)(V8 + off) = make_uint4(wv[0], wv[1], wv[2], wv[3]);
}

// ---- kernel 2: out = W + CS*(U8 @ V8^T), wave-specialized two-tile ----
// Waves 0-3 own tile A (cols +0..128), waves 4-7 tile B (cols +128..256);
// each wave holds ONE acc[8][4] (128 regs) -> no spill. Phase 1 (iters
// 0-11): A computes, B stages. Phase 2 (12-23): A stages + runs tile-A's
// epilogue inline (3-region L rotation, NT W-loads/out-stores; wave-local
// counted vmcnt); B computes. Tail: tile-B epilogue, raw-barrier pipelined.
__global__ __launch_bounds__(512, 1) void gemm_kernel(
    const float* __restrict__ W,
    const char* __restrict__ U8,
    const char* __restrict__ V8,
    const float* __restrict__ csp,
    float* __restrict__ out)
{
    __shared__ char SM[148992];          // As 64K | Bs 32K | L 3x16896
    char* const As = SM;                 // 4 bufs x 16384 B (256 rows x 64 k)
    char* const Bs = SM + 65536;         // 4 bufs x 8192 B (128 cols x 64 k)
    float* const L = (float*)(SM + 98304);   // 3 regions x 32 x 132 f32

    const int tid = threadIdx.x;         // 0..511
    const int lane = tid & 63;
    const int wave = tid >> 6;           // 0..7
    const bool isA = wave < 4;
    const int wl = wave & 3;
    const int wr = (wave >> 1) & 1;
    const int wc = wave & 1;
    const int fr = lane & 15;
    const int fks = lane >> 4;

    // XCD rect swizzle: 256 blocks, 8 XCDs, 4(by) x 8(bxp) rect per XCD.
    const int bid = blockIdx.x;
    const int xcd = bid & 7;
    const int local = bid >> 3;
    const int by = ((xcd >> 1) << 2) + (local >> 3);
    const int bxp = ((xcd & 1) << 3) + (local & 7);

    const char* uPan = U8 + (size_t)by * PANEL_I8;
    const char* vPan = V8 + (size_t)bxp * PANEL_I8;
    const float CS = *csp;

    i32x4 acc[8][4] = {};                // tile A for waves 0-3, B for 4-7
    f32x4 wregA[2][4];
    f32x4 wregB[2][2];

    const int aO = (fks << 12) + ((wr * 128 + fr) << 4);
    const int bO = (fks << 11) + ((wc * 64 + fr) << 4);

    const int erow = by << 8;
    const int bcolA = bxp << 8;
    const int bcolB = bcolA + 128;

#define VWAIT(n) asm volatile("s_waitcnt vmcnt(" #n ")" ::: "memory")
#define LGKM()   asm volatile("s_waitcnt lgkmcnt(0)" ::: "memory")
#define BARR()   do { __builtin_amdgcn_s_barrier(); asm volatile("" ::: "memory"); } while (0)

    // stage slab s: A-content (s%12) -> As buf s&3; V half (s/12) -> Bs buf s&3
#define STAGE_AB(s) do {                                                     \
        const char* uS = uPan + (size_t)((s) % 12) * 16384;                  \
        char* aD = As + ((s) & 3) * 16384 + (wl << 10);                      \
        glds16c(uS + (wl << 10) + (lane << 4),               aD);            \
        glds16c(uS + 4096 + (wl << 10) + (lane << 4),        aD + 4096);     \
        glds16c(uS + 8192 + (wl << 10) + (lane << 4),        aD + 8192);     \
        glds16c(uS + 12288 + (wl << 10) + (lane << 4),       aD + 12288);    \
        const char* vS = vPan + (size_t)((s) % 12) * 16384 + ((s) / 12) * 2048; \
        char* bD = Bs + ((s) & 3) * 8192 + (wl << 10);                       \
        glds16c(vS + (((wl >> 1) + 0) << 12) + ((wl & 1) << 10) + (lane << 4), bD); \
        glds16c(vS + (((wl >> 1) + 2) << 12) + ((wl & 1) << 10) + (lane << 4), bD + 4096); \
    } while (0)

#define COMPUTE(buf) do {                                                    \
        i32x4 a[8], b[4];                                                    \
        _Pragma("unroll")                                                    \
        for (int fm = 0; fm < 8; ++fm)                                       \
            a[fm] = *(const i32x4*)(As + (buf) * 16384 + aO + fm * 256);     \
        _Pragma("unroll")                                                    \
        for (int fn = 0; fn < 4; ++fn)                                       \
            b[fn] = *(const i32x4*)(Bs + (buf) * 8192 + bO + fn * 256);      \
        _Pragma("unroll")                                                    \
        for (int fm = 0; fm < 8; ++fm)                                       \
            _Pragma("unroll")                                                \
            for (int fn = 0; fn < 4; ++fn)                                   \
                acc[fm][fn] = __builtin_amdgcn_mfma_i32_16x16x64_i8(         \
                    b[fn], a[fm], acc[fm][fn], 0, 0, 0);                     \
    } while (0)

    // epilogue-A helpers (256 A-threads; tid < 256)
#define WLA(c) do {                                                          \
        _Pragma("unroll")                                                    \
        for (int i = 0; i < 4; ++i) {                                        \
            const int e = i * 256 + tid;                                     \
            wregA[(c) & 1][i] = __builtin_nontemporal_load((const f32x4*)(   \
                W + (size_t)(erow + (c) * 32 + (e >> 5)) * NDIM              \
                  + bcolA + ((e & 31) << 2)));                               \
        }                                                                    \
    } while (0)
#define LWRA(c) do {                                                         \
        if (wr == ((c) >> 2)) {                                              \
            _Pragma("unroll")                                                \
            for (int f2 = 0; f2 < 2; ++f2)                                   \
                _Pragma("unroll")                                            \
                for (int fn = 0; fn < 4; ++fn) {                             \
                    f32x4 v;                                                 \
                    _Pragma("unroll")                                        \
                    for (int jj = 0; jj < 4; ++jj)                           \
                        v[jj] = CS * (float)acc[((c) & 3) * 2 + f2][fn][jj]; \
                    *(f32x4*)(L + ((c) % 3) * 4224 + (f2 * 16 + fr) * 132    \
                              + (wc << 6) + fn * 16 + (fks << 2)) = v;       \
                }                                                            \
        }                                                                    \
    } while (0)
#define STA(c) do {                                                          \
        _Pragma("unroll")                                                    \
        for (int i = 0; i < 4; ++i) {                                        \
            const int e = i * 256 + tid;                                     \
            const int rl = e >> 5;                                           \
            const int cg = e & 31;                                           \
            const f32x4 l4 = *(const f32x4*)(L + ((c) % 3) * 4224            \
                                             + rl * 132 + (cg << 2));        \
            f32x4 r4 = wregA[(c) & 1][i] + l4;                               \
            __builtin_nontemporal_store(r4, (f32x4*)(                        \
                out + (size_t)(erow + (c) * 32 + rl) * NDIM                  \
                    + bcolA + (cg << 2)));                                   \
        }                                                                    \
    } while (0)

    // epilogue-B helpers (all 512 threads; LWRB only B-waves)
#define WLB(c) do {                                                          \
        _Pragma("unroll")                                                    \
        for (int i = 0; i < 2; ++i) {                                        \
            const int e = i * 512 + tid;                                     \
            wregB[(c) & 1][i] = __builtin_nontemporal_load((const f32x4*)(   \
                W + (size_t)(erow + (c) * 32 + (e >> 5)) * NDIM              \
                  + bcolB + ((e & 31) << 2)));                               \
        }                                                                    \
    } while (0)
#define LWRB(c) do {                                                         \
        if (!isA && wr == ((c) >> 2)) {                                      \
            _Pragma("unroll")                                                \
            for (int f2 = 0; f2 < 2; ++f2)                                   \
                _Pragma("unroll")                                            \
                for (int fn = 0; fn < 4; ++fn) {                             \
                    f32x4 v;                                                 \
                    _Pragma("unroll")                                        \
                    for (int jj = 0; jj < 4; ++jj)                           \
                        v[jj] = CS * (float)acc[((c) & 3) * 2 + f2][fn][jj]; \
                    *(f32x4*)(L + ((c) & 1) * 4224 + (f2 * 16 + fr) * 132    \
                              + (wc << 6) + fn * 16 + (fks << 2)) = v;       \
                }                                                            \
        }                                                                    \
    } while (0)
#define STB(c) do {                                                          \
        _Pragma("unroll")                                                    \
        for (int i = 0; i < 2; ++i) {                                        \
            const int e = i * 512 + tid;                                     \
            const int rl = e >> 5;                                           \
            const int cg = e & 31;                                           \
            const f32x4 l4 = *(const f32x4*)(L + ((c) & 1) * 4224            \
                                             + rl * 132 + (cg << 2));        \
            f32x4 r4 = wregB[(c) & 1][i] + l4;                               \
            __builtin_nontemporal_store(r4, (f32x4*)(                        \
                out + (size_t)(erow + (c) * 32 + rl) * NDIM                  \
                    + bcolB + ((cg) << 2)));                                 \
        }                                                                    \
    } while (0)

    // ---- prologue: B-waves stage slabs 0,1 ----
    if (!isA) { STAGE_AB(0); STAGE_AB(1); VWAIT(6); }
    LGKM(); BARR();

    // ---- phase 1: iters 0..11 — A computes, B stages ----
#define P1(j) do {                                                           \
        if (!isA) { STAGE_AB((j) + 2); VWAIT(12); }                          \
        LGKM(); BARR();                                                      \
        if (isA) COMPUTE((j) & 3);                                           \
    } while (0)
    P1(0); P1(1); P1(2); P1(3); P1(4); P1(5);
    P1(6); P1(7); P1(8); P1(9); P1(10); P1(11);

    // ---- phase 2: iters 12..23 — B computes, A stages + epilogue-A ----
    // A-wave vmcnt audit (WLA=4, STAGE=6, STA=4 ops):
    // i=12 none; i=13 VW(16); i=14..19 VW(20); i=20 VW(16); i=21 VW(20);
    // i=22 VW(10); i=23 VW(0). B-wave: i=12 VW(6); i=13 VW(0); else none.
    if (isA) { WLA(0); STAGE_AB(14); LWRA(0); } else { VWAIT(6); }
    LGKM(); BARR();
    if (!isA) COMPUTE(0);

    if (isA) { WLA(1); STAGE_AB(15); LWRA(1); VWAIT(16); } else { VWAIT(0); }
    LGKM(); BARR();
    if (!isA) COMPUTE(1);
    if (isA) STA(0);

#define P2(i, c) do {                                                        \
        if (isA) { WLA(c); STAGE_AB((i) + 2); LWRA(c); VWAIT(20); }          \
        LGKM(); BARR();                                                      \
        if (!isA) COMPUTE((i) & 3);                                          \
        if (isA) STA((c) - 1);                                               \
    } while (0)
    P2(14, 2); P2(15, 3); P2(16, 4); P2(17, 5); P2(18, 6); P2(19, 7);

    if (isA) { STAGE_AB(22); VWAIT(16); }
    LGKM(); BARR();
    if (!isA) COMPUTE(0);            // 20&3
    if (isA) STA(7);

    if (isA) { STAGE_AB(23); VWAIT(20); }
    LGKM(); BARR();
    if (!isA) COMPUTE(1);            // 21&3

    if (isA) { VWAIT(10); }
    LGKM(); BARR();
    if (!isA) COMPUTE(2);            // 22&3

    if (isA) { VWAIT(0); }
    LGKM(); BARR();
    if (!isA) COMPUTE(3);            // 23&3

    // ---- tail: epilogue-B (all waves stream; B-waves own LWRB) ----
    WLB(0);
    LWRB(0);
    LGKM(); BARR();
    WLB(1); LWRB(1); VWAIT(2); STB(0);
    LGKM(); BARR();
    WLB(2); LWRB(2); VWAIT(4); STB(1);
    LGKM(); BARR();
    WLB(3); LWRB(3); VWAIT(4); STB(2);
    LGKM(); BARR();
    WLB(4); LWRB(4); VWAIT(4); STB(3);
    LGKM(); BARR();
    WLB(5); LWRB(5); VWAIT(4); STB(4);
    LGKM(); BARR();
    WLB(6); LWRB(6); VWAIT(4); STB(5);
    LGKM(); BARR();
    WLB(7); LWRB(7); VWAIT(4); STB(6);
    LGKM(); BARR();
    VWAIT(2); STB(7);

#undef VWAIT
#undef LGKM
#undef BARR
#undef STAGE_AB
#undef COMPUTE
#undef WLA
#undef LWRA
#undef STA
#undef WLB
#undef LWRB
#undef STB
#undef P1
#undef P2
}

extern "C" void kernel_launch(void* const* d_in, const int* in_sizes, int n_in,
                              void* d_out, int out_size, void* d_ws, size_t ws_size,
                              hipStream_t stream) {
    const float* weight = (const float*)d_in[0];
    const float* dw     = (const float*)d_in[1];
    const int*   fidx   = (const int*)d_in[2];
    float* out = (float*)d_out;

    char* ws = (char*)d_ws;
    char* U8 = ws;                               // 3,145,728 B
    char* V8 = ws + 3145728;                     // 3,145,728 B
    float* csp = (float*)(ws + 2 * 3145728);

    fill_uv<<<16 * 48, 256, 0, stream>>>(fidx, dw, U8, V8, csp);
    gemm_kernel<<<256, 512, 0, stream>>>(weight, U8, V8, csp, out);
}